// Round 1
// 982.930 us; speedup vs baseline: 1.1944x; 1.1944x over previous
//
#include <hip/hip_runtime.h>
#include <hip/hip_fp16.h>

#define D_MODEL 1024
#define NHEADS  16
#define DEPTH   64
#define BATCH   8
#define SEQ     1024

typedef __attribute__((ext_vector_type(4))) float    floatx4;
typedef __attribute__((ext_vector_type(8))) _Float16 half8;
typedef __attribute__((ext_vector_type(4))) _Float16 half4;

// ---- async global->LDS, 16B per lane (wave-uniform LDS base + lane*16) ----
static __device__ __forceinline__ void async16(const void* g, void* l) {
    auto gp = reinterpret_cast<const __attribute__((address_space(1))) unsigned int*>(
        reinterpret_cast<uintptr_t>(g));
    auto lp = reinterpret_cast<__attribute__((address_space(3))) unsigned int*>(
        reinterpret_cast<uintptr_t>(l));
    __builtin_amdgcn_global_load_lds(gp, lp, 16, 0, 0);
}

// ---- fp32 -> fp16 convert, float4 -> half4 ----
__global__ void cvt_f32_f16(const float* __restrict__ src, _Float16* __restrict__ dst, int n4) {
    int i = blockIdx.x * 256 + threadIdx.x;
    if (i >= n4) return;
    const float4 f = ((const float4*)src)[i];
    half4 o = { (_Float16)f.x, (_Float16)f.y, (_Float16)f.z, (_Float16)f.w };
    ((half4*)dst)[i] = o;
}

// ---- C[M,N] = A[M,K] @ Bw[N,K]^T + bias; A,Bw fp16, fp32 accumulate ----
// 128x128 tile, BK=64, global_load_lds staging, XOR-swizzled LDS chunks.
template <int OUT_HALF>
__global__ __launch_bounds__(256, 2) void gemm_bt(
    const _Float16* __restrict__ A, const _Float16* __restrict__ Bw,
    const float* __restrict__ bias, void* __restrict__ Cout,
    int M, int N, int K)
{
    __shared__ _Float16 sA[128 * 64];   // 16 KB, [row][8 chunks of 8 halfs], chunk XOR-swizzled
    __shared__ _Float16 sB[128 * 64];

    const int tid  = threadIdx.x;
    const int wave = tid >> 6, lane = tid & 63;
    const int quad = lane >> 4, l16 = lane & 15;
    const int bm = blockIdx.x, bn = blockIdx.y;
    const int wy = wave & 1, wx = wave >> 1;

    floatx4 acc[4][4] = {};

    const int srow = wave * 8 + (lane >> 3);          // staging row (+ r*32)
    const int kpp  = lane & 7;                        // physical 16B chunk within row

    for (int k0 = 0; k0 < K; k0 += 64) {
        __syncthreads();
#pragma unroll
        for (int r = 0; r < 4; ++r) {
            const int row = srow + r * 32;
            const int kpl = kpp ^ (row & 7);          // logical chunk to fetch (swizzle)
            const _Float16* gA = A  + (size_t)(bm * 128 + row) * K + k0 + kpl * 8;
            const _Float16* gB = Bw + (size_t)(bn * 128 + row) * K + k0 + kpl * 8;
            async16(gA, sA + (r * 256 + wave * 64) * 8);
            async16(gB, sB + (r * 256 + wave * 64) * 8);
        }
        __syncthreads();
#pragma unroll
        for (int ks = 0; ks < 2; ++ks) {
            half8 af[4], bf[4];
#pragma unroll
            for (int i = 0; i < 4; ++i) {
                const int rowA = wy * 64 + i * 16 + l16;
                af[i] = *(const half8*)(sA + rowA * 64 + (((ks * 4 + quad) ^ (rowA & 7)) * 8));
                const int rowB = wx * 64 + i * 16 + l16;
                bf[i] = *(const half8*)(sB + rowB * 64 + (((ks * 4 + quad) ^ (rowB & 7)) * 8));
            }
#pragma unroll
            for (int i = 0; i < 4; ++i)
#pragma unroll
                for (int j = 0; j < 4; ++j)
                    acc[i][j] = __builtin_amdgcn_mfma_f32_16x16x32_f16(af[i], bf[j], acc[i][j], 0, 0, 0);
        }
    }

#pragma unroll
    for (int i = 0; i < 4; ++i) {
        const int row0 = bm * 128 + wy * 64 + i * 16 + quad * 4;
#pragma unroll
        for (int j = 0; j < 4; ++j) {
            const int col = bn * 128 + wx * 64 + j * 16 + l16;
            const float bv = bias[col];
#pragma unroll
            for (int r = 0; r < 4; ++r) {
                const float vv = acc[i][j][r] + bv;
                if (OUT_HALF) ((_Float16*)Cout)[(size_t)(row0 + r) * N + col] = (_Float16)vv;
                else          ((float*)Cout)   [(size_t)(row0 + r) * N + col] = vv;
            }
        }
    }
}

// ---- V transpose: [B,S,D_MODEL] -> [B*H, DEPTH, S] so PV B-frags are contiguous ----
__global__ __launch_bounds__(256) void transpose_v(const _Float16* __restrict__ vp,
                                                   _Float16* __restrict__ vt) {
    __shared__ _Float16 t[64][72];
    const int tid = threadIdx.x;
    const int s0 = blockIdx.x * 64;
    const int bh = blockIdx.y;
    const int b = bh >> 4, h = bh & 15;
    {
        const int si = tid >> 2, dj = (tid & 3) * 16;
        const _Float16* src = vp + (size_t)(b * SEQ + s0 + si) * D_MODEL + h * 64 + dj;
        *(half8*)&t[si][dj]     = *(const half8*)src;
        *(half8*)&t[si][dj + 8] = *(const half8*)(src + 8);
    }
    __syncthreads();
    {
        const int d = tid >> 2, sj = (tid & 3) * 16;
        _Float16* dst = vt + (size_t)(bh * 64 + d) * SEQ + s0 + sj;
        half8 v0, v1;
#pragma unroll
        for (int j = 0; j < 8; ++j) { v0[j] = t[sj + j][d]; v1[j] = t[sj + 8 + j][d]; }
        *(half8*)dst       = v0;
        *(half8*)(dst + 8) = v1;
    }
}

// ---- fused scores + mask + softmax + attn-write + PV ----
// Swapped-operand QK^T (T12 pattern): lane (quad,l16) owns Q-row l16,
// keys ct*16+quad*4+{0..3} -> scores live in 64 VGPRs, softmax in-register.
// P written ONCE to fp16 LDS with 8B-chunk XOR swizzle -> conflict-free PV reads.
__global__ __launch_bounds__(256, 3) void attn_fused(
    const _Float16* __restrict__ qp, const _Float16* __restrict__ kp,
    const _Float16* __restrict__ vt, const int* __restrict__ mask,
    float* __restrict__ attn, _Float16* __restrict__ ctx)
{
    __shared__ _Float16 pb[16 * 1024];   // 32 KB fp16 P, swizzled
    __shared__ float maddend[1024];      // 4 KB: 0 or -inf per key col
    __shared__ float red0[4][16];        // per-wave row max
    __shared__ float red1[4][16];        // per-wave row sum

    const int tid  = threadIdx.x;
    const int wave = tid >> 6, lane = tid & 63;
    const int quad = lane >> 4, l16 = lane & 15;
    const int q0 = blockIdx.x * 16;
    const int bh = blockIdx.y;
    const int b = bh >> 4, h = bh & 15;
    const float scale = 1.0f / (sqrtf(64.0f) + 1e-8f);
    const float NEGINF = -__builtin_inff();

    // mask addend -> LDS (col 0 always valid)
    {
        const int c = tid * 4;
        const int* mrow = mask + b * (SEQ - 1);
        float4 a4;
        a4.x = (c == 0) ? 0.f : (mrow[c - 1] ? 0.f : NEGINF);
        a4.y = mrow[c + 0] ? 0.f : NEGINF;
        a4.z = mrow[c + 1] ? 0.f : NEGINF;
        a4.w = mrow[c + 2] ? 0.f : NEGINF;
        *(float4*)&maddend[c] = a4;
    }

    // Q fragments (used as MFMA B-operand: n = l16 = Q row, k = quad*8+j)
    const half8 qf0 = *(const half8*)(qp + (size_t)(b * SEQ + q0 + l16) * D_MODEL + h * 64 + quad * 8);
    const half8 qf1 = *(const half8*)(qp + (size_t)(b * SEQ + q0 + l16) * D_MODEL + h * 64 + 32 + quad * 8);
    __syncthreads();

    // Phase 1: S = scale * K Q^T (swapped) + mask; wave w covers keys [w*256,(w+1)*256)
    float s[16][4];
#pragma unroll
    for (int t = 0; t < 16; ++t) {
        const int ct = wave * 16 + t;
        const half8 kf0 = *(const half8*)(kp + (size_t)(b * SEQ + ct * 16 + l16) * D_MODEL + h * 64 + quad * 8);
        const half8 kf1 = *(const half8*)(kp + (size_t)(b * SEQ + ct * 16 + l16) * D_MODEL + h * 64 + 32 + quad * 8);
        floatx4 a = {0.f, 0.f, 0.f, 0.f};
        a = __builtin_amdgcn_mfma_f32_16x16x32_f16(kf0, qf0, a, 0, 0, 0);
        a = __builtin_amdgcn_mfma_f32_16x16x32_f16(kf1, qf1, a, 0, 0, 0);
        const float4 ma = *(const float4*)&maddend[ct * 16 + quad * 4];
        s[t][0] = a[0] * scale + ma.x;
        s[t][1] = a[1] * scale + ma.y;
        s[t][2] = a[2] * scale + ma.z;
        s[t][3] = a[3] * scale + ma.w;
    }

    // Phase 2: row max + row sum (row = l16). In-lane, cross-quad shfl, cross-wave LDS.
    float pm = NEGINF;
#pragma unroll
    for (int t = 0; t < 16; ++t)
#pragma unroll
        for (int r = 0; r < 4; ++r) pm = fmaxf(pm, s[t][r]);
    pm = fmaxf(pm, __shfl_xor(pm, 16, 64));
    pm = fmaxf(pm, __shfl_xor(pm, 32, 64));
    if (lane < 16) red0[wave][lane] = pm;
    __syncthreads();
    const float m = fmaxf(fmaxf(red0[0][l16], red0[1][l16]),
                          fmaxf(red0[2][l16], red0[3][l16]));

    float ps = 0.f;
#pragma unroll
    for (int t = 0; t < 16; ++t)
#pragma unroll
        for (int r = 0; r < 4; ++r) { s[t][r] = __expf(s[t][r] - m); ps += s[t][r]; }
    ps += __shfl_xor(ps, 16, 64);
    ps += __shfl_xor(ps, 32, 64);
    if (lane < 16) red1[wave][lane] = ps;
    __syncthreads();
    const float inv = 1.0f / (red1[0][l16] + red1[1][l16] + red1[2][l16] + red1[3][l16]);

    // Phase 3: normalize; float4 attn store (lane holds 4 consecutive cols);
    // P -> fp16 LDS at 8B chunk (ct*4+quad) ^ ((row&7)<<1)  [write 2-way = free]
    float* arow = attn + ((size_t)bh * SEQ + q0 + l16) * SEQ;
#pragma unroll
    for (int t = 0; t < 16; ++t) {
        const int ct = wave * 16 + t;
        float4 p4;
        p4.x = s[t][0] * inv; p4.y = s[t][1] * inv;
        p4.z = s[t][2] * inv; p4.w = s[t][3] * inv;
        *(float4*)&arow[ct * 16 + quad * 4] = p4;
        half4 hp = { (_Float16)p4.x, (_Float16)p4.y, (_Float16)p4.z, (_Float16)p4.w };
        const int chunk = (ct * 4 + quad) ^ ((l16 & 7) << 1);
        *(half4*)((char*)pb + l16 * 2048 + (chunk << 3)) = hp;
    }
    __syncthreads();

    // Phase 4: O[16,64] = P[16,1024] @ V; wave = depth col-tile.
    // 16B chunk read (k0/8+quad) ^ (l16&7): 8 lanes/bank-group = b128 minimum (conflict-free).
    floatx4 oacc = {0.f, 0.f, 0.f, 0.f};
    const _Float16* vrow = vt + (size_t)(bh * 64 + wave * 16 + l16) * SEQ;
#pragma unroll 4
    for (int k0 = 0; k0 < 1024; k0 += 32) {
        const int mchunk = ((k0 >> 3) + quad) ^ (l16 & 7);
        const half8 af = *(const half8*)((char*)pb + l16 * 2048 + (mchunk << 4));
        const half8 vf = *(const half8*)(vrow + k0 + quad * 8);
        oacc = __builtin_amdgcn_mfma_f32_16x16x32_f16(af, vf, oacc, 0, 0, 0);
    }
#pragma unroll
    for (int r = 0; r < 4; ++r)
        ctx[(size_t)(b * SEQ + q0 + quad * 4 + r) * D_MODEL + h * 64 + wave * 16 + l16] = (_Float16)oacc[r];
}

extern "C" void kernel_launch(void* const* d_in, const int* in_sizes, int n_in,
                              void* d_out, int out_size, void* d_ws, size_t ws_size,
                              hipStream_t stream) {
    (void)in_sizes; (void)n_in; (void)out_size; (void)ws_size;
    const float* q    = (const float*)d_in[0];
    const float* k    = (const float*)d_in[1];
    const float* v    = (const float*)d_in[2];
    const int*   mask = (const int*)d_in[3];
    const float* wq_w = (const float*)d_in[4];
    const float* wq_b = (const float*)d_in[5];
    const float* wk_w = (const float*)d_in[6];
    const float* wk_b = (const float*)d_in[7];
    const float* wv_w = (const float*)d_in[8];
    const float* wv_b = (const float*)d_in[9];
    const float* dw   = (const float*)d_in[10];
    const float* db   = (const float*)d_in[11];

    float* outp  = (float*)d_out;
    float* attnp = outp + (size_t)BATCH * SEQ * D_MODEL;   // tuple: [output | attn]

    const size_t NQKV = (size_t)BATCH * SEQ * D_MODEL;     // 8388608
    const size_t NW   = (size_t)D_MODEL * D_MODEL;         // 1048576
    _Float16* tmpA  = (_Float16*)d_ws;      // input fp16 / later vT   (16.8 MB)
    _Float16* tmpW  = tmpA + NQKV;          // weight fp16             (2 MB)
    _Float16* qproj = tmpW + NW;            // (16.8 MB)
    _Float16* kproj = qproj + NQKV;         // (16.8 MB)
    _Float16* vproj = kproj + NQKV;         // later ctx (16.8 MB)  => ws total ~69.2 MB

    const int M = BATCH * SEQ;              // 8192
    const dim3 gg(M / 128, D_MODEL / 128);  // 64 x 8

    // Q path
    cvt_f32_f16<<<NQKV / 4 / 256, 256, 0, stream>>>(q, tmpA, (int)(NQKV / 4));
    cvt_f32_f16<<<NW / 4 / 256,  256, 0, stream>>>(wq_w, tmpW, (int)(NW / 4));
    gemm_bt<1><<<gg, 256, 0, stream>>>(tmpA, tmpW, wq_b, qproj, M, D_MODEL, D_MODEL);
    // K path
    cvt_f32_f16<<<NQKV / 4 / 256, 256, 0, stream>>>(k, tmpA, (int)(NQKV / 4));
    cvt_f32_f16<<<NW / 4 / 256,  256, 0, stream>>>(wk_w, tmpW, (int)(NW / 4));
    gemm_bt<1><<<gg, 256, 0, stream>>>(tmpA, tmpW, wk_b, kproj, M, D_MODEL, D_MODEL);
    // V path
    cvt_f32_f16<<<NQKV / 4 / 256, 256, 0, stream>>>(v, tmpA, (int)(NQKV / 4));
    cvt_f32_f16<<<NW / 4 / 256,  256, 0, stream>>>(wv_w, tmpW, (int)(NW / 4));
    gemm_bt<1><<<gg, 256, 0, stream>>>(tmpA, tmpW, wv_b, vproj, M, D_MODEL, D_MODEL);
    // vT into tmpA (vb dead)
    transpose_v<<<dim3(SEQ / 64, BATCH * NHEADS), 256, 0, stream>>>(vproj, tmpA);
    // fused attention: reads qproj/kproj/vT, writes attn (d_out) + ctx (vproj region, dead)
    attn_fused<<<dim3(SEQ / 16, BATCH * NHEADS), 256, 0, stream>>>(qproj, kproj, tmpA, mask, attnp, vproj);
    // dense
    cvt_f32_f16<<<NW / 4 / 256, 256, 0, stream>>>(dw, tmpW, (int)(NW / 4));
    gemm_bt<0><<<gg, 256, 0, stream>>>(vproj, tmpW, db, outp, M, D_MODEL, D_MODEL);
}

// Round 3
// 950.797 us; speedup vs baseline: 1.2347x; 1.0338x over previous
//
#include <hip/hip_runtime.h>
#include <hip/hip_fp16.h>

#define D_MODEL 1024
#define NHEADS  16
#define DEPTH   64
#define BATCH   8
#define SEQ     1024

typedef __attribute__((ext_vector_type(4))) float    floatx4;
typedef __attribute__((ext_vector_type(8))) _Float16 half8;
typedef __attribute__((ext_vector_type(4))) _Float16 half4;

// ---- async global->LDS, 16B per lane (wave-uniform LDS base + lane*16) ----
static __device__ __forceinline__ void async16(const void* g, void* l) {
    auto gp = reinterpret_cast<const __attribute__((address_space(1))) unsigned int*>(
        reinterpret_cast<uintptr_t>(g));
    auto lp = reinterpret_cast<__attribute__((address_space(3))) unsigned int*>(
        reinterpret_cast<uintptr_t>(l));
    __builtin_amdgcn_global_load_lds(gp, lp, 16, 0, 0);
}

// ---- fp32 -> fp16 convert, float4 -> half4 ----
__global__ void cvt_f32_f16(const float* __restrict__ src, _Float16* __restrict__ dst, int n4) {
    int i = blockIdx.x * 256 + threadIdx.x;
    if (i >= n4) return;
    const float4 f = ((const float4*)src)[i];
    half4 o = { (_Float16)f.x, (_Float16)f.y, (_Float16)f.z, (_Float16)f.w };
    ((half4*)dst)[i] = o;
}

// ---- C[M,N] = A[M,K] @ Bw[N,K]^T + bias; A,Bw fp16, fp32 accumulate ----
// 128x128 tile, BK=64, global_load_lds staging, XOR-swizzled LDS chunks.
template <int OUT_HALF>
__global__ __launch_bounds__(256, 2) void gemm_bt(
    const _Float16* __restrict__ A, const _Float16* __restrict__ Bw,
    const float* __restrict__ bias, void* __restrict__ Cout,
    int M, int N, int K)
{
    __shared__ _Float16 sA[128 * 64];   // 16 KB, [row][8 chunks of 8 halfs], chunk XOR-swizzled
    __shared__ _Float16 sB[128 * 64];

    const int tid  = threadIdx.x;
    const int wave = tid >> 6, lane = tid & 63;
    const int quad = lane >> 4, l16 = lane & 15;
    const int bm = blockIdx.x, bn = blockIdx.y;
    const int wy = wave & 1, wx = wave >> 1;

    floatx4 acc[4][4] = {};

    const int srow = wave * 8 + (lane >> 3);          // staging row (+ r*32)
    const int kpp  = lane & 7;                        // physical 16B chunk within row

    for (int k0 = 0; k0 < K; k0 += 64) {
        __syncthreads();
#pragma unroll
        for (int r = 0; r < 4; ++r) {
            const int row = srow + r * 32;
            const int kpl = kpp ^ (row & 7);          // logical chunk to fetch (swizzle)
            const _Float16* gA = A  + (size_t)(bm * 128 + row) * K + k0 + kpl * 8;
            const _Float16* gB = Bw + (size_t)(bn * 128 + row) * K + k0 + kpl * 8;
            async16(gA, sA + (r * 256 + wave * 64) * 8);
            async16(gB, sB + (r * 256 + wave * 64) * 8);
        }
        __syncthreads();
#pragma unroll
        for (int ks = 0; ks < 2; ++ks) {
            half8 af[4], bf[4];
#pragma unroll
            for (int i = 0; i < 4; ++i) {
                const int rowA = wy * 64 + i * 16 + l16;
                af[i] = *(const half8*)(sA + rowA * 64 + (((ks * 4 + quad) ^ (rowA & 7)) * 8));
                const int rowB = wx * 64 + i * 16 + l16;
                bf[i] = *(const half8*)(sB + rowB * 64 + (((ks * 4 + quad) ^ (rowB & 7)) * 8));
            }
#pragma unroll
            for (int i = 0; i < 4; ++i)
#pragma unroll
                for (int j = 0; j < 4; ++j)
                    acc[i][j] = __builtin_amdgcn_mfma_f32_16x16x32_f16(af[i], bf[j], acc[i][j], 0, 0, 0);
        }
    }

#pragma unroll
    for (int i = 0; i < 4; ++i) {
        const int row0 = bm * 128 + wy * 64 + i * 16 + quad * 4;
#pragma unroll
        for (int j = 0; j < 4; ++j) {
            const int col = bn * 128 + wx * 64 + j * 16 + l16;
            const float bv = bias[col];
#pragma unroll
            for (int r = 0; r < 4; ++r) {
                const float vv = acc[i][j][r] + bv;
                if (OUT_HALF) ((_Float16*)Cout)[(size_t)(row0 + r) * N + col] = (_Float16)vv;
                else          ((float*)Cout)   [(size_t)(row0 + r) * N + col] = vv;
            }
        }
    }
}

// ---- V transpose: [B,S,D_MODEL] -> [B*H, DEPTH, S] so PV B-frags are contiguous ----
__global__ __launch_bounds__(256) void transpose_v(const _Float16* __restrict__ vp,
                                                   _Float16* __restrict__ vt) {
    __shared__ _Float16 t[64][72];
    const int tid = threadIdx.x;
    const int s0 = blockIdx.x * 64;
    const int bh = blockIdx.y;
    const int b = bh >> 4, h = bh & 15;
    {
        const int si = tid >> 2, dj = (tid & 3) * 16;
        const _Float16* src = vp + (size_t)(b * SEQ + s0 + si) * D_MODEL + h * 64 + dj;
        *(half8*)&t[si][dj]     = *(const half8*)src;
        *(half8*)&t[si][dj + 8] = *(const half8*)(src + 8);
    }
    __syncthreads();
    {
        const int d = tid >> 2, sj = (tid & 3) * 16;
        _Float16* dst = vt + (size_t)(bh * 64 + d) * SEQ + s0 + sj;
        half8 v0, v1;
#pragma unroll
        for (int j = 0; j < 8; ++j) { v0[j] = t[sj + j][d]; v1[j] = t[sj + 8 + j][d]; }
        *(half8*)dst       = v0;
        *(half8*)(dst + 8) = v1;
    }
}

// ---- fused scores + mask + softmax + attn-write + PV ----
// Swapped-operand QK^T: lane (quad,l16) owns Q-row l16, keys ct*16+quad*4+{0..3};
// scores in 64 VGPRs, softmax in-register. P stored ONCE to fp16 LDS (8B-chunk
// XOR swizzle). Attn global write is sourced from LDS, fully coalesced (1KB/instr),
// and interleaved 1:2 into the PV MFMA loop so the 64KB/block store burst drains
// under compute. LDS 36.5KB -> 4 blocks/CU.
__global__ __launch_bounds__(256, 4) void attn_fused(
    const _Float16* __restrict__ qp, const _Float16* __restrict__ kp,
    const _Float16* __restrict__ vt, const int* __restrict__ mask,
    float* __restrict__ attn, _Float16* __restrict__ ctx)
{
    __shared__ _Float16 pb[16 * 1024];   // 32 KB fp16 P, swizzled (8B chunk ^ ((row&7)<<1))
    __shared__ float maddend[1024];      // 4 KB: 0 or -inf per key col
    __shared__ float red0[4][16];        // per-wave row max
    __shared__ float red1[4][16];        // per-wave row sum

    const int tid  = threadIdx.x;
    const int wave = tid >> 6, lane = tid & 63;
    const int quad = lane >> 4, l16 = lane & 15;
    const int q0 = blockIdx.x * 16;
    const int bh = blockIdx.y;
    const int b = bh >> 4, h = bh & 15;
    const float scale = 1.0f / (sqrtf(64.0f) + 1e-8f);
    const float NEGINF = -__builtin_inff();

    // mask addend -> LDS (col 0 always valid)
    {
        const int c = tid * 4;
        const int* mrow = mask + b * (SEQ - 1);
        float4 a4;
        a4.x = (c == 0) ? 0.f : (mrow[c - 1] ? 0.f : NEGINF);
        a4.y = mrow[c + 0] ? 0.f : NEGINF;
        a4.z = mrow[c + 1] ? 0.f : NEGINF;
        a4.w = mrow[c + 2] ? 0.f : NEGINF;
        *(float4*)&maddend[c] = a4;
    }

    // Q fragments (used as MFMA B-operand: n = l16 = Q row, k = quad*8+j)
    const half8 qf0 = *(const half8*)(qp + (size_t)(b * SEQ + q0 + l16) * D_MODEL + h * 64 + quad * 8);
    const half8 qf1 = *(const half8*)(qp + (size_t)(b * SEQ + q0 + l16) * D_MODEL + h * 64 + 32 + quad * 8);
    __syncthreads();

    // Phase 1: S = scale * K Q^T (swapped) + mask; wave w covers keys [w*256,(w+1)*256)
    float s[16][4];
#pragma unroll
    for (int t = 0; t < 16; ++t) {
        const int ct = wave * 16 + t;
        const half8 kf0 = *(const half8*)(kp + (size_t)(b * SEQ + ct * 16 + l16) * D_MODEL + h * 64 + quad * 8);
        const half8 kf1 = *(const half8*)(kp + (size_t)(b * SEQ + ct * 16 + l16) * D_MODEL + h * 64 + 32 + quad * 8);
        floatx4 a = {0.f, 0.f, 0.f, 0.f};
        a = __builtin_amdgcn_mfma_f32_16x16x32_f16(kf0, qf0, a, 0, 0, 0);
        a = __builtin_amdgcn_mfma_f32_16x16x32_f16(kf1, qf1, a, 0, 0, 0);
        const float4 ma = *(const float4*)&maddend[ct * 16 + quad * 4];
        s[t][0] = a[0] * scale + ma.x;
        s[t][1] = a[1] * scale + ma.y;
        s[t][2] = a[2] * scale + ma.z;
        s[t][3] = a[3] * scale + ma.w;
    }

    // Phase 2: row max + row sum (row = l16). In-lane, cross-quad shfl, cross-wave LDS.
    float pm = NEGINF;
#pragma unroll
    for (int t = 0; t < 16; ++t)
#pragma unroll
        for (int r = 0; r < 4; ++r) pm = fmaxf(pm, s[t][r]);
    pm = fmaxf(pm, __shfl_xor(pm, 16, 64));
    pm = fmaxf(pm, __shfl_xor(pm, 32, 64));
    if (lane < 16) red0[wave][lane] = pm;
    __syncthreads();
    const float m = fmaxf(fmaxf(red0[0][l16], red0[1][l16]),
                          fmaxf(red0[2][l16], red0[3][l16]));

    float ps = 0.f;
#pragma unroll
    for (int t = 0; t < 16; ++t)
#pragma unroll
        for (int r = 0; r < 4; ++r) { s[t][r] = __expf(s[t][r] - m); ps += s[t][r]; }
    ps += __shfl_xor(ps, 16, 64);
    ps += __shfl_xor(ps, 32, 64);
    if (lane < 16) red1[wave][lane] = ps;
    __syncthreads();
    const float inv = 1.0f / (red1[0][l16] + red1[1][l16] + red1[2][l16] + red1[3][l16]);

    // Phase 3: normalize; P -> fp16 LDS only. 8B chunk (ct*4+quad) ^ ((row&7)<<1).
#pragma unroll
    for (int t = 0; t < 16; ++t) {
        const int ct = wave * 16 + t;
        half4 hp = { (_Float16)(s[t][0] * inv), (_Float16)(s[t][1] * inv),
                     (_Float16)(s[t][2] * inv), (_Float16)(s[t][3] * inv) };
        const int chunk = (ct * 4 + quad) ^ ((l16 & 7) << 1);
        *(half4*)((char*)pb + l16 * 2048 + (chunk << 3)) = hp;
    }
    __syncthreads();

    // Phase 4: O[16,64] = P[16,1024] @ V (wave = depth col-tile), interleaved with
    // the attn global write (wave writes q-rows wave*4..+3, 1KB coalesced/instr).
    floatx4 oacc = {0.f, 0.f, 0.f, 0.f};
    const _Float16* vrow = vt + (size_t)(bh * 64 + wave * 16 + l16) * SEQ;
#pragma unroll
    for (int it = 0; it < 32; ++it) {
        const int k0 = it * 32;
        const int mchunk = ((k0 >> 3) + quad) ^ (l16 & 7);          // 16B chunk ^ (row&7)
        const half8 af = *(const half8*)((char*)pb + l16 * 2048 + (mchunk << 4));
        const half8 vf = *(const half8*)(vrow + k0 + quad * 8);
        oacc = __builtin_amdgcn_mfma_f32_16x16x32_f16(af, vf, oacc, 0, 0, 0);
        if (it & 1) {
            const int w = it >> 1;                    // 0..15: 16 write-chunks per wave
            const int r = wave * 4 + (w >> 2);        // q-row owned by this wave
            const int g = w & 3;                      // 256-col group
            const int c8 = g * 64 + lane;             // logical 8B chunk in row r
            const int pc = c8 ^ ((r & 7) << 1);       // physical (swizzled)
            const half4 hv = *(const half4*)((char*)pb + r * 2048 + (pc << 3));
            float4 f;
            f.x = (float)hv[0]; f.y = (float)hv[1]; f.z = (float)hv[2]; f.w = (float)hv[3];
            *(float4*)(attn + ((size_t)bh * SEQ + q0 + r) * SEQ + c8 * 4) = f;
        }
    }
#pragma unroll
    for (int r = 0; r < 4; ++r)
        ctx[(size_t)(b * SEQ + q0 + quad * 4 + r) * D_MODEL + h * 64 + wave * 16 + l16] = (_Float16)oacc[r];
}

extern "C" void kernel_launch(void* const* d_in, const int* in_sizes, int n_in,
                              void* d_out, int out_size, void* d_ws, size_t ws_size,
                              hipStream_t stream) {
    (void)in_sizes; (void)n_in; (void)out_size; (void)ws_size;
    const float* q    = (const float*)d_in[0];
    const float* k    = (const float*)d_in[1];
    const float* v    = (const float*)d_in[2];
    const int*   mask = (const int*)d_in[3];
    const float* wq_w = (const float*)d_in[4];
    const float* wq_b = (const float*)d_in[5];
    const float* wk_w = (const float*)d_in[6];
    const float* wk_b = (const float*)d_in[7];
    const float* wv_w = (const float*)d_in[8];
    const float* wv_b = (const float*)d_in[9];
    const float* dw   = (const float*)d_in[10];
    const float* db   = (const float*)d_in[11];

    float* outp  = (float*)d_out;
    float* attnp = outp + (size_t)BATCH * SEQ * D_MODEL;   // tuple: [output | attn]

    const size_t NQKV = (size_t)BATCH * SEQ * D_MODEL;     // 8388608
    const size_t NW   = (size_t)D_MODEL * D_MODEL;         // 1048576
    _Float16* tmpA  = (_Float16*)d_ws;      // input fp16 / later vT   (16.8 MB)
    _Float16* tmpW  = tmpA + NQKV;          // weight fp16             (2 MB)
    _Float16* qproj = tmpW + NW;            // (16.8 MB)
    _Float16* kproj = qproj + NQKV;         // (16.8 MB)
    _Float16* vproj = kproj + NQKV;         // later ctx (16.8 MB)  => ws total ~69.2 MB

    const int M = BATCH * SEQ;              // 8192
    const dim3 gg(M / 128, D_MODEL / 128);  // 64 x 8

    // Q path
    cvt_f32_f16<<<NQKV / 4 / 256, 256, 0, stream>>>(q, tmpA, (int)(NQKV / 4));
    cvt_f32_f16<<<NW / 4 / 256,  256, 0, stream>>>(wq_w, tmpW, (int)(NW / 4));
    gemm_bt<1><<<gg, 256, 0, stream>>>(tmpA, tmpW, wq_b, qproj, M, D_MODEL, D_MODEL);
    // K path
    cvt_f32_f16<<<NQKV / 4 / 256, 256, 0, stream>>>(k, tmpA, (int)(NQKV / 4));
    cvt_f32_f16<<<NW / 4 / 256,  256, 0, stream>>>(wk_w, tmpW, (int)(NW / 4));
    gemm_bt<1><<<gg, 256, 0, stream>>>(tmpA, tmpW, wk_b, kproj, M, D_MODEL, D_MODEL);
    // V path
    cvt_f32_f16<<<NQKV / 4 / 256, 256, 0, stream>>>(v, tmpA, (int)(NQKV / 4));
    cvt_f32_f16<<<NW / 4 / 256,  256, 0, stream>>>(wv_w, tmpW, (int)(NW / 4));
    gemm_bt<1><<<gg, 256, 0, stream>>>(tmpA, tmpW, wv_b, vproj, M, D_MODEL, D_MODEL);
    // vT into tmpA (vb dead)
    transpose_v<<<dim3(SEQ / 64, BATCH * NHEADS), 256, 0, stream>>>(vproj, tmpA);
    // fused attention: reads qproj/kproj/vT, writes attn (d_out) + ctx (vproj region, dead)
    attn_fused<<<dim3(SEQ / 16, BATCH * NHEADS), 256, 0, stream>>>(qproj, kproj, tmpA, mask, attnp, vproj);
    // dense
    cvt_f32_f16<<<NW / 4 / 256, 256, 0, stream>>>(dw, tmpW, (int)(NW / 4));
    gemm_bt<0><<<gg, 256, 0, stream>>>(vproj, tmpW, db, outp, M, D_MODEL, D_MODEL);
}

// Round 4
// 944.048 us; speedup vs baseline: 1.2435x; 1.0071x over previous
//
#include <hip/hip_runtime.h>
#include <hip/hip_fp16.h>

#define D_MODEL 1024
#define NHEADS  16
#define DEPTH   64
#define BATCH   8
#define SEQ     1024

typedef __attribute__((ext_vector_type(4))) float    floatx4;
typedef __attribute__((ext_vector_type(8))) _Float16 half8;
typedef __attribute__((ext_vector_type(4))) _Float16 half4;

// ---- async global->LDS, 16B per lane (wave-uniform LDS base + lane*16) ----
static __device__ __forceinline__ void async16(const void* g, void* l) {
    auto gp = reinterpret_cast<const __attribute__((address_space(1))) unsigned int*>(
        reinterpret_cast<uintptr_t>(g));
    auto lp = reinterpret_cast<__attribute__((address_space(3))) unsigned int*>(
        reinterpret_cast<uintptr_t>(l));
    __builtin_amdgcn_global_load_lds(gp, lp, 16, 0, 0);
}

// ---- fp32 -> fp16 convert, float4 -> half4 ----
__global__ void cvt_f32_f16(const float* __restrict__ src, _Float16* __restrict__ dst, int n4) {
    int i = blockIdx.x * 256 + threadIdx.x;
    if (i >= n4) return;
    const float4 f = ((const float4*)src)[i];
    half4 o = { (_Float16)f.x, (_Float16)f.y, (_Float16)f.z, (_Float16)f.w };
    ((half4*)dst)[i] = o;
}

// ---- C[M,N] = A[M,K] @ Bw[N,K]^T + bias; A,Bw fp16, fp32 accumulate ----
// 128x128 tile, BK=64, DOUBLE-BUFFERED global_load_lds staging (T3 2-phase):
// issue next tile's loads BEFORE computing current tile; single
// vmcnt(0)+barrier per K-step (the __syncthreads at loop end). Load latency
// hides under 32 MFMA + ds_reads. LDS 64KB -> 2 blocks/CU.
template <int OUT_HALF>
__global__ __launch_bounds__(256, 2) void gemm_bt(
    const _Float16* __restrict__ A, const _Float16* __restrict__ Bw,
    const float* __restrict__ bias, void* __restrict__ Cout,
    int M, int N, int K)
{
    __shared__ _Float16 sA[2][128 * 64];   // 2 x 16 KB, chunk XOR-swizzled
    __shared__ _Float16 sB[2][128 * 64];

    const int tid  = threadIdx.x;
    const int wave = tid >> 6, lane = tid & 63;
    const int quad = lane >> 4, l16 = lane & 15;
    const int bm = blockIdx.x, bn = blockIdx.y;
    const int wy = wave & 1, wx = wave >> 1;

    floatx4 acc[4][4] = {};

    const int srow = wave * 8 + (lane >> 3);          // staging row (+ r*32)
    const int kpp  = lane & 7;                        // physical 16B chunk within row

    const _Float16* Abase = A  + (size_t)(bm * 128) * K;
    const _Float16* Bbase = Bw + (size_t)(bn * 128) * K;

#define STAGE(buf, kk)                                                          \
    _Pragma("unroll")                                                           \
    for (int r = 0; r < 4; ++r) {                                               \
        const int row = srow + r * 32;                                          \
        const int kpl = kpp ^ (row & 7);                                        \
        async16(Abase + (size_t)row * K + (kk) + kpl * 8,                       \
                sA[buf] + (r * 256 + wave * 64) * 8);                           \
        async16(Bbase + (size_t)row * K + (kk) + kpl * 8,                       \
                sB[buf] + (r * 256 + wave * 64) * 8);                           \
    }

    STAGE(0, 0);
    __syncthreads();                       // vmcnt(0) drain + barrier: tile0 ready

    int cur = 0;
    for (int k0 = 0; k0 < K; k0 += 64) {
        if (k0 + 64 < K) { STAGE(cur ^ 1, k0 + 64); }   // issue-early, not waited
#pragma unroll
        for (int ks = 0; ks < 2; ++ks) {
            half8 af[4], bf[4];
#pragma unroll
            for (int i = 0; i < 4; ++i) {
                const int rowA = wy * 64 + i * 16 + l16;
                af[i] = *(const half8*)(sA[cur] + rowA * 64 + (((ks * 4 + quad) ^ (rowA & 7)) * 8));
                const int rowB = wx * 64 + i * 16 + l16;
                bf[i] = *(const half8*)(sB[cur] + rowB * 64 + (((ks * 4 + quad) ^ (rowB & 7)) * 8));
            }
#pragma unroll
            for (int i = 0; i < 4; ++i)
#pragma unroll
                for (int j = 0; j < 4; ++j)
                    acc[i][j] = __builtin_amdgcn_mfma_f32_16x16x32_f16(af[i], bf[j], acc[i][j], 0, 0, 0);
        }
        __syncthreads();                   // drains next-tile loads; LDS reuse safe
        cur ^= 1;
    }
#undef STAGE

#pragma unroll
    for (int i = 0; i < 4; ++i) {
        const int row0 = bm * 128 + wy * 64 + i * 16 + quad * 4;
#pragma unroll
        for (int j = 0; j < 4; ++j) {
            const int col = bn * 128 + wx * 64 + j * 16 + l16;
            const float bv = bias[col];
#pragma unroll
            for (int r = 0; r < 4; ++r) {
                const float vv = acc[i][j][r] + bv;
                if (OUT_HALF) ((_Float16*)Cout)[(size_t)(row0 + r) * N + col] = (_Float16)vv;
                else          ((float*)Cout)   [(size_t)(row0 + r) * N + col] = vv;
            }
        }
    }
}

// ---- V transpose: [B,S,D_MODEL] -> [B*H, DEPTH, S] so PV B-frags are contiguous ----
__global__ __launch_bounds__(256) void transpose_v(const _Float16* __restrict__ vp,
                                                   _Float16* __restrict__ vt) {
    __shared__ _Float16 t[64][72];
    const int tid = threadIdx.x;
    const int s0 = blockIdx.x * 64;
    const int bh = blockIdx.y;
    const int b = bh >> 4, h = bh & 15;
    {
        const int si = tid >> 2, dj = (tid & 3) * 16;
        const _Float16* src = vp + (size_t)(b * SEQ + s0 + si) * D_MODEL + h * 64 + dj;
        *(half8*)&t[si][dj]     = *(const half8*)src;
        *(half8*)&t[si][dj + 8] = *(const half8*)(src + 8);
    }
    __syncthreads();
    {
        const int d = tid >> 2, sj = (tid & 3) * 16;
        _Float16* dst = vt + (size_t)(bh * 64 + d) * SEQ + s0 + sj;
        half8 v0, v1;
#pragma unroll
        for (int j = 0; j < 8; ++j) { v0[j] = t[sj + j][d]; v1[j] = t[sj + 8 + j][d]; }
        *(half8*)dst       = v0;
        *(half8*)(dst + 8) = v1;
    }
}

// ---- fused scores + mask + softmax + attn-write + PV ----
// Swapped-operand QK^T: lane (quad,l16) owns Q-row l16, keys ct*16+quad*4+{0..3};
// scores in 64 VGPRs, softmax in-register. P stored ONCE to fp16 LDS (8B-chunk
// XOR swizzle). Attn global write is sourced from LDS, fully coalesced (1KB/instr),
// and interleaved 1:2 into the PV MFMA loop so the 64KB/block store burst drains
// under compute. LDS 36.5KB -> 4 blocks/CU.
__global__ __launch_bounds__(256, 4) void attn_fused(
    const _Float16* __restrict__ qp, const _Float16* __restrict__ kp,
    const _Float16* __restrict__ vt, const int* __restrict__ mask,
    float* __restrict__ attn, _Float16* __restrict__ ctx)
{
    __shared__ _Float16 pb[16 * 1024];   // 32 KB fp16 P, swizzled (8B chunk ^ ((row&7)<<1))
    __shared__ float maddend[1024];      // 4 KB: 0 or -inf per key col
    __shared__ float red0[4][16];        // per-wave row max
    __shared__ float red1[4][16];        // per-wave row sum

    const int tid  = threadIdx.x;
    const int wave = tid >> 6, lane = tid & 63;
    const int quad = lane >> 4, l16 = lane & 15;
    const int q0 = blockIdx.x * 16;
    const int bh = blockIdx.y;
    const int b = bh >> 4, h = bh & 15;
    const float scale = 1.0f / (sqrtf(64.0f) + 1e-8f);
    const float NEGINF = -__builtin_inff();

    // mask addend -> LDS (col 0 always valid)
    {
        const int c = tid * 4;
        const int* mrow = mask + b * (SEQ - 1);
        float4 a4;
        a4.x = (c == 0) ? 0.f : (mrow[c - 1] ? 0.f : NEGINF);
        a4.y = mrow[c + 0] ? 0.f : NEGINF;
        a4.z = mrow[c + 1] ? 0.f : NEGINF;
        a4.w = mrow[c + 2] ? 0.f : NEGINF;
        *(float4*)&maddend[c] = a4;
    }

    // Q fragments (used as MFMA B-operand: n = l16 = Q row, k = quad*8+j)
    const half8 qf0 = *(const half8*)(qp + (size_t)(b * SEQ + q0 + l16) * D_MODEL + h * 64 + quad * 8);
    const half8 qf1 = *(const half8*)(qp + (size_t)(b * SEQ + q0 + l16) * D_MODEL + h * 64 + 32 + quad * 8);
    __syncthreads();

    // Phase 1: S = scale * K Q^T (swapped) + mask; wave w covers keys [w*256,(w+1)*256)
    float s[16][4];
#pragma unroll
    for (int t = 0; t < 16; ++t) {
        const int ct = wave * 16 + t;
        const half8 kf0 = *(const half8*)(kp + (size_t)(b * SEQ + ct * 16 + l16) * D_MODEL + h * 64 + quad * 8);
        const half8 kf1 = *(const half8*)(kp + (size_t)(b * SEQ + ct * 16 + l16) * D_MODEL + h * 64 + 32 + quad * 8);
        floatx4 a = {0.f, 0.f, 0.f, 0.f};
        a = __builtin_amdgcn_mfma_f32_16x16x32_f16(kf0, qf0, a, 0, 0, 0);
        a = __builtin_amdgcn_mfma_f32_16x16x32_f16(kf1, qf1, a, 0, 0, 0);
        const float4 ma = *(const float4*)&maddend[ct * 16 + quad * 4];
        s[t][0] = a[0] * scale + ma.x;
        s[t][1] = a[1] * scale + ma.y;
        s[t][2] = a[2] * scale + ma.z;
        s[t][3] = a[3] * scale + ma.w;
    }

    // Phase 2: row max + row sum (row = l16). In-lane, cross-quad shfl, cross-wave LDS.
    float pm = NEGINF;
#pragma unroll
    for (int t = 0; t < 16; ++t)
#pragma unroll
        for (int r = 0; r < 4; ++r) pm = fmaxf(pm, s[t][r]);
    pm = fmaxf(pm, __shfl_xor(pm, 16, 64));
    pm = fmaxf(pm, __shfl_xor(pm, 32, 64));
    if (lane < 16) red0[wave][lane] = pm;
    __syncthreads();
    const float m = fmaxf(fmaxf(red0[0][l16], red0[1][l16]),
                          fmaxf(red0[2][l16], red0[3][l16]));

    float ps = 0.f;
#pragma unroll
    for (int t = 0; t < 16; ++t)
#pragma unroll
        for (int r = 0; r < 4; ++r) { s[t][r] = __expf(s[t][r] - m); ps += s[t][r]; }
    ps += __shfl_xor(ps, 16, 64);
    ps += __shfl_xor(ps, 32, 64);
    if (lane < 16) red1[wave][lane] = ps;
    __syncthreads();
    const float inv = 1.0f / (red1[0][l16] + red1[1][l16] + red1[2][l16] + red1[3][l16]);

    // Phase 3: normalize; P -> fp16 LDS only. 8B chunk (ct*4+quad) ^ ((row&7)<<1).
#pragma unroll
    for (int t = 0; t < 16; ++t) {
        const int ct = wave * 16 + t;
        half4 hp = { (_Float16)(s[t][0] * inv), (_Float16)(s[t][1] * inv),
                     (_Float16)(s[t][2] * inv), (_Float16)(s[t][3] * inv) };
        const int chunk = (ct * 4 + quad) ^ ((l16 & 7) << 1);
        *(half4*)((char*)pb + l16 * 2048 + (chunk << 3)) = hp;
    }
    __syncthreads();

    // Phase 4: O[16,64] = P[16,1024] @ V (wave = depth col-tile), interleaved with
    // the attn global write (wave writes q-rows wave*4..+3, 1KB coalesced/instr).
    floatx4 oacc = {0.f, 0.f, 0.f, 0.f};
    const _Float16* vrow = vt + (size_t)(bh * 64 + wave * 16 + l16) * SEQ;
#pragma unroll
    for (int it = 0; it < 32; ++it) {
        const int k0 = it * 32;
        const int mchunk = ((k0 >> 3) + quad) ^ (l16 & 7);          // 16B chunk ^ (row&7)
        const half8 af = *(const half8*)((char*)pb + l16 * 2048 + (mchunk << 4));
        const half8 vf = *(const half8*)(vrow + k0 + quad * 8);
        oacc = __builtin_amdgcn_mfma_f32_16x16x32_f16(af, vf, oacc, 0, 0, 0);
        if (it & 1) {
            const int w = it >> 1;                    // 0..15: 16 write-chunks per wave
            const int r = wave * 4 + (w >> 2);        // q-row owned by this wave
            const int g = w & 3;                      // 256-col group
            const int c8 = g * 64 + lane;             // logical 8B chunk in row r
            const int pc = c8 ^ ((r & 7) << 1);       // physical (swizzled)
            const half4 hv = *(const half4*)((char*)pb + r * 2048 + (pc << 3));
            float4 f;
            f.x = (float)hv[0]; f.y = (float)hv[1]; f.z = (float)hv[2]; f.w = (float)hv[3];
            *(float4*)(attn + ((size_t)bh * SEQ + q0 + r) * SEQ + c8 * 4) = f;
        }
    }
#pragma unroll
    for (int r = 0; r < 4; ++r)
        ctx[(size_t)(b * SEQ + q0 + quad * 4 + r) * D_MODEL + h * 64 + wave * 16 + l16] = (_Float16)oacc[r];
}

extern "C" void kernel_launch(void* const* d_in, const int* in_sizes, int n_in,
                              void* d_out, int out_size, void* d_ws, size_t ws_size,
                              hipStream_t stream) {
    (void)in_sizes; (void)n_in; (void)out_size; (void)ws_size;
    const float* q    = (const float*)d_in[0];
    const float* k    = (const float*)d_in[1];
    const float* v    = (const float*)d_in[2];
    const int*   mask = (const int*)d_in[3];
    const float* wq_w = (const float*)d_in[4];
    const float* wq_b = (const float*)d_in[5];
    const float* wk_w = (const float*)d_in[6];
    const float* wk_b = (const float*)d_in[7];
    const float* wv_w = (const float*)d_in[8];
    const float* wv_b = (const float*)d_in[9];
    const float* dw   = (const float*)d_in[10];
    const float* db   = (const float*)d_in[11];

    float* outp  = (float*)d_out;
    float* attnp = outp + (size_t)BATCH * SEQ * D_MODEL;   // tuple: [output | attn]

    const size_t NQKV = (size_t)BATCH * SEQ * D_MODEL;     // 8388608
    const size_t NW   = (size_t)D_MODEL * D_MODEL;         // 1048576
    _Float16* tmpA  = (_Float16*)d_ws;      // input fp16 / later vT   (16.8 MB)
    _Float16* tmpW  = tmpA + NQKV;          // weight fp16             (2 MB)
    _Float16* qproj = tmpW + NW;            // (16.8 MB)
    _Float16* kproj = qproj + NQKV;         // (16.8 MB)
    _Float16* vproj = kproj + NQKV;         // later ctx (16.8 MB)  => ws total ~69.2 MB

    const int M = BATCH * SEQ;              // 8192
    const dim3 gg(M / 128, D_MODEL / 128);  // 64 x 8

    // Q path
    cvt_f32_f16<<<NQKV / 4 / 256, 256, 0, stream>>>(q, tmpA, (int)(NQKV / 4));
    cvt_f32_f16<<<NW / 4 / 256,  256, 0, stream>>>(wq_w, tmpW, (int)(NW / 4));
    gemm_bt<1><<<gg, 256, 0, stream>>>(tmpA, tmpW, wq_b, qproj, M, D_MODEL, D_MODEL);
    // K path
    cvt_f32_f16<<<NQKV / 4 / 256, 256, 0, stream>>>(k, tmpA, (int)(NQKV / 4));
    cvt_f32_f16<<<NW / 4 / 256,  256, 0, stream>>>(wk_w, tmpW, (int)(NW / 4));
    gemm_bt<1><<<gg, 256, 0, stream>>>(tmpA, tmpW, wk_b, kproj, M, D_MODEL, D_MODEL);
    // V path
    cvt_f32_f16<<<NQKV / 4 / 256, 256, 0, stream>>>(v, tmpA, (int)(NQKV / 4));
    cvt_f32_f16<<<NW / 4 / 256,  256, 0, stream>>>(wv_w, tmpW, (int)(NW / 4));
    gemm_bt<1><<<gg, 256, 0, stream>>>(tmpA, tmpW, wv_b, vproj, M, D_MODEL, D_MODEL);
    // vT into tmpA (vb dead)
    transpose_v<<<dim3(SEQ / 64, BATCH * NHEADS), 256, 0, stream>>>(vproj, tmpA);
    // fused attention: reads qproj/kproj/vT, writes attn (d_out) + ctx (vproj region, dead)
    attn_fused<<<dim3(SEQ / 16, BATCH * NHEADS), 256, 0, stream>>>(qproj, kproj, tmpA, mask, attnp, vproj);
    // dense
    cvt_f32_f16<<<NW / 4 / 256, 256, 0, stream>>>(dw, tmpW, (int)(NW / 4));
    gemm_bt<0><<<gg, 256, 0, stream>>>(vproj, tmpW, db, outp, M, D_MODEL, D_MODEL);
}

// Round 5
// 925.569 us; speedup vs baseline: 1.2684x; 1.0200x over previous
//
#include <hip/hip_runtime.h>
#include <hip/hip_fp16.h>

#define D_MODEL 1024
#define NHEADS  16
#define DEPTH   64
#define BATCH   8
#define SEQ     1024

typedef __attribute__((ext_vector_type(4))) float    floatx4;
typedef __attribute__((ext_vector_type(8))) _Float16 half8;
typedef __attribute__((ext_vector_type(4))) _Float16 half4;

// ---- async global->LDS, 16B per lane (wave-uniform LDS base + lane*16) ----
static __device__ __forceinline__ void async16(const void* g, void* l) {
    auto gp = reinterpret_cast<const __attribute__((address_space(1))) unsigned int*>(
        reinterpret_cast<uintptr_t>(g));
    auto lp = reinterpret_cast<__attribute__((address_space(3))) unsigned int*>(
        reinterpret_cast<uintptr_t>(l));
    __builtin_amdgcn_global_load_lds(gp, lp, 16, 0, 0);
}

// ---- fp32 -> fp16 convert, float4 granularity ----
__global__ void cvt_f32_f16(const float* __restrict__ src, _Float16* __restrict__ dst, int n4) {
    int i = blockIdx.x * 256 + threadIdx.x;
    if (i >= n4) return;
    const float4 f = ((const float4*)src)[i];
    half4 o = { (_Float16)f.x, (_Float16)f.y, (_Float16)f.z, (_Float16)f.w };
    ((half4*)dst)[i] = o;
}

// ---- fused cvt: q|k|v (3 x 2^21 float4) then wq|wk|wv (3 x 2^18 float4) ----
// dst is one contiguous fp16 region. Range boundaries are multiples of 256 ->
// the branch is block-uniform.
__global__ __launch_bounds__(256) void cvt_all(
    const float* __restrict__ q, const float* __restrict__ k, const float* __restrict__ v,
    const float* __restrict__ w0, const float* __restrict__ w1, const float* __restrict__ w2,
    _Float16* __restrict__ dst)
{
    const int i = blockIdx.x * 256 + threadIdx.x;
    const int IN4 = 1 << 21;                 // (B*S*D)/4 float4 per input tensor
    const int W4  = 1 << 18;                 // (D*D)/4 float4 per weight
    const float* src; int off;
    if (i < 3 * IN4) {
        const int which = i >> 21; off = i & (IN4 - 1);
        src = which == 0 ? q : (which == 1 ? k : v);
    } else {
        const int j = i - 3 * IN4;
        const int which = j >> 18; off = j & (W4 - 1);
        src = which == 0 ? w0 : (which == 1 ? w1 : w2);
    }
    const float4 f = ((const float4*)src)[off];
    half4 o = { (_Float16)f.x, (_Float16)f.y, (_Float16)f.z, (_Float16)f.w };
    ((half4*)dst)[i] = o;
}

// ---- C[M,N] = A[M,K] @ Bw[N,K]^T + bias; A,Bw fp16, fp32 accumulate ----
// 128x128 tile, BK=64, single-buffered global_load_lds staging (dbuf proved
// neutral -> trade LDS for occupancy: 32KB, 3 blocks/CU).
// blockIdx.z batches independent GEMMs (QKV projections): A += z*M*K etc.
template <int OUT_HALF>
__global__ __launch_bounds__(256, 3) void gemm_bt(
    const _Float16* __restrict__ A, const _Float16* __restrict__ Bw,
    const float* __restrict__ bias0, const float* __restrict__ bias1,
    const float* __restrict__ bias2, void* __restrict__ Cout,
    int M, int N, int K)
{
    __shared__ _Float16 sA[128 * 64];   // 16 KB, [row][8 chunks of 8 halfs], XOR-swizzled
    __shared__ _Float16 sB[128 * 64];

    const int tid  = threadIdx.x;
    const int wave = tid >> 6, lane = tid & 63;
    const int quad = lane >> 4, l16 = lane & 15;
    const int bm = blockIdx.x, bn = blockIdx.y, bz = blockIdx.z;
    const int wy = wave & 1, wx = wave >> 1;

    const float* bias = bz == 0 ? bias0 : (bz == 1 ? bias1 : bias2);
    const _Float16* Abase = A  + (size_t)bz * M * K + (size_t)(bm * 128) * K;
    const _Float16* Bbase = Bw + (size_t)bz * N * K + (size_t)(bn * 128) * K;

    floatx4 acc[4][4] = {};

    const int srow = wave * 8 + (lane >> 3);          // staging row (+ r*32)
    const int kpp  = lane & 7;                        // physical 16B chunk within row

    for (int k0 = 0; k0 < K; k0 += 64) {
        __syncthreads();
#pragma unroll
        for (int r = 0; r < 4; ++r) {
            const int row = srow + r * 32;
            const int kpl = kpp ^ (row & 7);          // logical chunk to fetch (swizzle)
            async16(Abase + (size_t)row * K + k0 + kpl * 8, sA + (r * 256 + wave * 64) * 8);
            async16(Bbase + (size_t)row * K + k0 + kpl * 8, sB + (r * 256 + wave * 64) * 8);
        }
        __syncthreads();
#pragma unroll
        for (int ks = 0; ks < 2; ++ks) {
            half8 af[4], bf[4];
#pragma unroll
            for (int i = 0; i < 4; ++i) {
                const int rowA = wy * 64 + i * 16 + l16;
                af[i] = *(const half8*)(sA + rowA * 64 + (((ks * 4 + quad) ^ (rowA & 7)) * 8));
                const int rowB = wx * 64 + i * 16 + l16;
                bf[i] = *(const half8*)(sB + rowB * 64 + (((ks * 4 + quad) ^ (rowB & 7)) * 8));
            }
#pragma unroll
            for (int i = 0; i < 4; ++i)
#pragma unroll
                for (int j = 0; j < 4; ++j)
                    acc[i][j] = __builtin_amdgcn_mfma_f32_16x16x32_f16(af[i], bf[j], acc[i][j], 0, 0, 0);
        }
    }

    const size_t czoff = (size_t)bz * M * N;
#pragma unroll
    for (int i = 0; i < 4; ++i) {
        const int row0 = bm * 128 + wy * 64 + i * 16 + quad * 4;
#pragma unroll
        for (int j = 0; j < 4; ++j) {
            const int col = bn * 128 + wx * 64 + j * 16 + l16;
            const float bv = bias[col];
#pragma unroll
            for (int r = 0; r < 4; ++r) {
                const float vv = acc[i][j][r] + bv;
                if (OUT_HALF) ((_Float16*)Cout)[czoff + (size_t)(row0 + r) * N + col] = (_Float16)vv;
                else          ((float*)Cout)   [czoff + (size_t)(row0 + r) * N + col] = vv;
            }
        }
    }
}

// ---- V transpose: [B,S,D_MODEL] -> [B*H, DEPTH, S] so PV B-frags are contiguous ----
__global__ __launch_bounds__(256) void transpose_v(const _Float16* __restrict__ vp,
                                                   _Float16* __restrict__ vt) {
    __shared__ _Float16 t[64][72];
    const int tid = threadIdx.x;
    const int s0 = blockIdx.x * 64;
    const int bh = blockIdx.y;
    const int b = bh >> 4, h = bh & 15;
    {
        const int si = tid >> 2, dj = (tid & 3) * 16;
        const _Float16* src = vp + (size_t)(b * SEQ + s0 + si) * D_MODEL + h * 64 + dj;
        *(half8*)&t[si][dj]     = *(const half8*)src;
        *(half8*)&t[si][dj + 8] = *(const half8*)(src + 8);
    }
    __syncthreads();
    {
        const int d = tid >> 2, sj = (tid & 3) * 16;
        _Float16* dst = vt + (size_t)(bh * 64 + d) * SEQ + s0 + sj;
        half8 v0, v1;
#pragma unroll
        for (int j = 0; j < 8; ++j) { v0[j] = t[sj + j][d]; v1[j] = t[sj + 8 + j][d]; }
        *(half8*)dst       = v0;
        *(half8*)(dst + 8) = v1;
    }
}

// ---- fused scores + mask + softmax + attn-write + PV ----
// Swapped-operand QK^T: lane (quad,l16) owns Q-row l16, keys ct*16+quad*4+{0..3};
// scores in 64 VGPRs, softmax in-register. P stored ONCE to fp16 LDS (8B-chunk
// XOR swizzle). Attn global write is sourced from LDS, fully coalesced (1KB/instr),
// and interleaved 1:2 into the PV MFMA loop so the 64KB/block store burst drains
// under compute. LDS 36.5KB -> 4 blocks/CU.
__global__ __launch_bounds__(256, 4) void attn_fused(
    const _Float16* __restrict__ qp, const _Float16* __restrict__ kp,
    const _Float16* __restrict__ vt, const int* __restrict__ mask,
    float* __restrict__ attn, _Float16* __restrict__ ctx)
{
    __shared__ _Float16 pb[16 * 1024];   // 32 KB fp16 P, swizzled (8B chunk ^ ((row&7)<<1))
    __shared__ float maddend[1024];      // 4 KB: 0 or -inf per key col
    __shared__ float red0[4][16];        // per-wave row max
    __shared__ float red1[4][16];        // per-wave row sum

    const int tid  = threadIdx.x;
    const int wave = tid >> 6, lane = tid & 63;
    const int quad = lane >> 4, l16 = lane & 15;
    const int q0 = blockIdx.x * 16;
    const int bh = blockIdx.y;
    const int b = bh >> 4, h = bh & 15;
    const float scale = 1.0f / (sqrtf(64.0f) + 1e-8f);
    const float NEGINF = -__builtin_inff();

    // mask addend -> LDS (col 0 always valid)
    {
        const int c = tid * 4;
        const int* mrow = mask + b * (SEQ - 1);
        float4 a4;
        a4.x = (c == 0) ? 0.f : (mrow[c - 1] ? 0.f : NEGINF);
        a4.y = mrow[c + 0] ? 0.f : NEGINF;
        a4.z = mrow[c + 1] ? 0.f : NEGINF;
        a4.w = mrow[c + 2] ? 0.f : NEGINF;
        *(float4*)&maddend[c] = a4;
    }

    // Q fragments (used as MFMA B-operand: n = l16 = Q row, k = quad*8+j)
    const half8 qf0 = *(const half8*)(qp + (size_t)(b * SEQ + q0 + l16) * D_MODEL + h * 64 + quad * 8);
    const half8 qf1 = *(const half8*)(qp + (size_t)(b * SEQ + q0 + l16) * D_MODEL + h * 64 + 32 + quad * 8);
    __syncthreads();

    // Phase 1: S = scale * K Q^T (swapped) + mask; wave w covers keys [w*256,(w+1)*256)
    float s[16][4];
#pragma unroll
    for (int t = 0; t < 16; ++t) {
        const int ct = wave * 16 + t;
        const half8 kf0 = *(const half8*)(kp + (size_t)(b * SEQ + ct * 16 + l16) * D_MODEL + h * 64 + quad * 8);
        const half8 kf1 = *(const half8*)(kp + (size_t)(b * SEQ + ct * 16 + l16) * D_MODEL + h * 64 + 32 + quad * 8);
        floatx4 a = {0.f, 0.f, 0.f, 0.f};
        a = __builtin_amdgcn_mfma_f32_16x16x32_f16(kf0, qf0, a, 0, 0, 0);
        a = __builtin_amdgcn_mfma_f32_16x16x32_f16(kf1, qf1, a, 0, 0, 0);
        const float4 ma = *(const float4*)&maddend[ct * 16 + quad * 4];
        s[t][0] = a[0] * scale + ma.x;
        s[t][1] = a[1] * scale + ma.y;
        s[t][2] = a[2] * scale + ma.z;
        s[t][3] = a[3] * scale + ma.w;
    }

    // Phase 2: row max + row sum (row = l16). In-lane, cross-quad shfl, cross-wave LDS.
    float pm = NEGINF;
#pragma unroll
    for (int t = 0; t < 16; ++t)
#pragma unroll
        for (int r = 0; r < 4; ++r) pm = fmaxf(pm, s[t][r]);
    pm = fmaxf(pm, __shfl_xor(pm, 16, 64));
    pm = fmaxf(pm, __shfl_xor(pm, 32, 64));
    if (lane < 16) red0[wave][lane] = pm;
    __syncthreads();
    const float m = fmaxf(fmaxf(red0[0][l16], red0[1][l16]),
                          fmaxf(red0[2][l16], red0[3][l16]));

    float ps = 0.f;
#pragma unroll
    for (int t = 0; t < 16; ++t)
#pragma unroll
        for (int r = 0; r < 4; ++r) { s[t][r] = __expf(s[t][r] - m); ps += s[t][r]; }
    ps += __shfl_xor(ps, 16, 64);
    ps += __shfl_xor(ps, 32, 64);
    if (lane < 16) red1[wave][lane] = ps;
    __syncthreads();
    const float inv = 1.0f / (red1[0][l16] + red1[1][l16] + red1[2][l16] + red1[3][l16]);

    // Phase 3: normalize; P -> fp16 LDS only. 8B chunk (ct*4+quad) ^ ((row&7)<<1).
#pragma unroll
    for (int t = 0; t < 16; ++t) {
        const int ct = wave * 16 + t;
        half4 hp = { (_Float16)(s[t][0] * inv), (_Float16)(s[t][1] * inv),
                     (_Float16)(s[t][2] * inv), (_Float16)(s[t][3] * inv) };
        const int chunk = (ct * 4 + quad) ^ ((l16 & 7) << 1);
        *(half4*)((char*)pb + l16 * 2048 + (chunk << 3)) = hp;
    }
    __syncthreads();

    // Phase 4: O[16,64] = P[16,1024] @ V (wave = depth col-tile), interleaved with
    // the attn global write (wave writes q-rows wave*4..+3, 1KB coalesced/instr).
    floatx4 oacc = {0.f, 0.f, 0.f, 0.f};
    const _Float16* vrow = vt + (size_t)(bh * 64 + wave * 16 + l16) * SEQ;
#pragma unroll
    for (int it = 0; it < 32; ++it) {
        const int k0 = it * 32;
        const int mchunk = ((k0 >> 3) + quad) ^ (l16 & 7);          // 16B chunk ^ (row&7)
        const half8 af = *(const half8*)((char*)pb + l16 * 2048 + (mchunk << 4));
        const half8 vf = *(const half8*)(vrow + k0 + quad * 8);
        oacc = __builtin_amdgcn_mfma_f32_16x16x32_f16(af, vf, oacc, 0, 0, 0);
        if (it & 1) {
            const int w = it >> 1;                    // 0..15: 16 write-chunks per wave
            const int r = wave * 4 + (w >> 2);        // q-row owned by this wave
            const int g = w & 3;                      // 256-col group
            const int c8 = g * 64 + lane;             // logical 8B chunk in row r
            const int pc = c8 ^ ((r & 7) << 1);       // physical (swizzled)
            const half4 hv = *(const half4*)((char*)pb + r * 2048 + (pc << 3));
            float4 f;
            f.x = (float)hv[0]; f.y = (float)hv[1]; f.z = (float)hv[2]; f.w = (float)hv[3];
            *(float4*)(attn + ((size_t)bh * SEQ + q0 + r) * SEQ + c8 * 4) = f;
        }
    }
#pragma unroll
    for (int r = 0; r < 4; ++r)
        ctx[(size_t)(b * SEQ + q0 + quad * 4 + r) * D_MODEL + h * 64 + wave * 16 + l16] = (_Float16)oacc[r];
}

extern "C" void kernel_launch(void* const* d_in, const int* in_sizes, int n_in,
                              void* d_out, int out_size, void* d_ws, size_t ws_size,
                              hipStream_t stream) {
    (void)in_sizes; (void)n_in; (void)out_size; (void)ws_size;
    const float* q    = (const float*)d_in[0];
    const float* k    = (const float*)d_in[1];
    const float* v    = (const float*)d_in[2];
    const int*   mask = (const int*)d_in[3];
    const float* wq_w = (const float*)d_in[4];
    const float* wq_b = (const float*)d_in[5];
    const float* wk_w = (const float*)d_in[6];
    const float* wk_b = (const float*)d_in[7];
    const float* wv_w = (const float*)d_in[8];
    const float* wv_b = (const float*)d_in[9];
    const float* dw   = (const float*)d_in[10];
    const float* db   = (const float*)d_in[11];

    float* outp  = (float*)d_out;
    float* attnp = outp + (size_t)BATCH * SEQ * D_MODEL;   // tuple: [output | attn]

    const size_t NQKV = (size_t)BATCH * SEQ * D_MODEL;     // 8388608
    const size_t NW   = (size_t)D_MODEL * D_MODEL;         // 1048576
    const int    M    = BATCH * SEQ;                       // 8192

    // ws: 4 x 16.8 MB = 67.1 MB
    _Float16* qproj = (_Float16*)d_ws;
    _Float16* kproj = qproj + NQKV;
    _Float16* vproj = kproj + NQKV;        // reused as ctx after transpose_v
    _Float16* vtb   = vproj + NQKV;        // vT; reused for dense-weight fp16 after attn? NO:
                                           // dw16 goes here only after attn (vT dead then)
    // fp16 staging scratch lives in the (not-yet-written) attn output region:
    // [qf16|kf16|vf16|wq16|wk16|wv16] = 56.6 MB of the 536 MB attn buffer.
    _Float16* sc     = (_Float16*)attnp;
    _Float16* w3f16  = sc + 3 * NQKV;
    _Float16* ctx    = vproj;
    _Float16* dw16   = vtb;                // after attn_fused, vT is dead

    // 1) all six fp32->fp16 conversions in one launch
    const int CVT_BLOCKS = (3 * (1 << 21) + 3 * (1 << 18)) / 256;   // 27648
    cvt_all<<<CVT_BLOCKS, 256, 0, stream>>>(q, k, v, wq_w, wk_w, wv_w, sc);
    // 2) Q,K,V projections batched over blockIdx.z
    gemm_bt<1><<<dim3(M / 128, D_MODEL / 128, 3), 256, 0, stream>>>(
        sc, w3f16, wq_b, wk_b, wv_b, qproj, M, D_MODEL, D_MODEL);
    // 3) V transpose
    transpose_v<<<dim3(SEQ / 64, BATCH * NHEADS), 256, 0, stream>>>(vproj, vtb);
    // 4) fused attention (overwrites the staging scratch with the real attn output)
    attn_fused<<<dim3(SEQ / 16, BATCH * NHEADS), 256, 0, stream>>>(
        qproj, kproj, vtb, mask, attnp, ctx);
    // 5) dense weight cvt (into dead vT region) + dense GEMM
    cvt_f32_f16<<<(int)(NW / 4 / 256), 256, 0, stream>>>(dw, dw16, (int)(NW / 4));
    gemm_bt<0><<<dim3(M / 128, D_MODEL / 128, 1), 256, 0, stream>>>(
        ctx, dw16, db, db, db, outp, M, D_MODEL, D_MODEL);
}